// Round 5
// baseline (1473.847 us; speedup 1.0000x reference)
//
#include <hip/hip_runtime.h>

#define NF 16          // feature width of h / output
#define FI 8           // input feature width
#define NPB 128        // nodes per bucket
#define BSH 7          // log2(NPB)
#define CHUNK 32768    // edges per partition chunk
#define MAXNB 1024     // max buckets supported by LDS tables
#define GT 512         // gather block threads

// ---------------------------------------------------------------------------
// h1 = x @ W1   (n x 8) @ (8 x 16)
// ---------------------------------------------------------------------------
__global__ void k_h1(const float* __restrict__ x, const float* __restrict__ W1,
                     float* __restrict__ h, int n) {
    int i = blockIdx.x * blockDim.x + threadIdx.x;
    if (i >= n) return;
    const float4* xp = reinterpret_cast<const float4*>(x + (size_t)i * FI);
    float4 a = xp[0], b = xp[1];
    float xi[FI] = {a.x, a.y, a.z, a.w, b.x, b.y, b.z, b.w};
    float* hp = h + (size_t)i * NF;
    #pragma unroll
    for (int f = 0; f < NF; ++f) {
        float acc = 0.f;
        #pragma unroll
        for (int k = 0; k < FI; ++k) acc = fmaf(xi[k], W1[k * NF + f], acc);
        hp[f] = acc;
    }
}

// h2 = relu(h) @ W2, in place (row i reads/writes only row i)
__global__ void k_h2(float* __restrict__ io, const float* __restrict__ W2, int n) {
    int i = blockIdx.x * blockDim.x + threadIdx.x;
    if (i >= n) return;
    float hi[NF];
    float4* ip = reinterpret_cast<float4*>(io + (size_t)i * NF);
    #pragma unroll
    for (int q = 0; q < 4; ++q) {
        float4 v = ip[q];
        hi[q * 4 + 0] = fmaxf(v.x, 0.f);
        hi[q * 4 + 1] = fmaxf(v.y, 0.f);
        hi[q * 4 + 2] = fmaxf(v.z, 0.f);
        hi[q * 4 + 3] = fmaxf(v.w, 0.f);
    }
    float o[NF];
    #pragma unroll
    for (int f = 0; f < NF; ++f) {
        float acc = 0.f;
        #pragma unroll
        for (int k = 0; k < NF; ++k) acc = fmaf(hi[k], W2[k * NF + f], acc);
        o[f] = acc;
    }
    #pragma unroll
    for (int q = 0; q < 4; ++q)
        ip[q] = make_float4(o[q*4+0], o[q*4+1], o[q*4+2], o[q*4+3]);
}

// ======================= radix-partition CSR build =========================

// per-chunk LDS histogram of bucket ids -> table[b*NC + chunk]
__global__ void k_phist(const int* __restrict__ col, int* __restrict__ table,
                        int NB, int NC, int E) {
    __shared__ int lh[MAXNB];
    int c0 = blockIdx.x * CHUNK;
    int c1 = min(c0 + CHUNK, E);
    for (int i = threadIdx.x; i < NB; i += blockDim.x) lh[i] = 0;
    __syncthreads();
    for (int e = c0 + threadIdx.x; e < c1; e += blockDim.x)
        atomicAdd(&lh[col[e] >> BSH], 1);
    __syncthreads();
    for (int b = threadIdx.x; b < NB; b += blockDim.x)
        table[(size_t)b * NC + blockIdx.x] = lh[b];
}

// per bucket: exclusive scan over its NC chunk counts (in place); btot[b]=total
__global__ void k_scan_chunks(int* __restrict__ table, int* __restrict__ btot,
                              int NC) {
    __shared__ int lds[256];
    int b = blockIdx.x, t = threadIdx.x;
    int v = (t < NC) ? table[(size_t)b * NC + t] : 0;
    lds[t] = v;
    __syncthreads();
    for (int d = 1; d < 256; d <<= 1) {
        int add = (t >= d) ? lds[t - d] : 0;
        __syncthreads();
        lds[t] += add;
        __syncthreads();
    }
    if (t == 255) btot[b] = lds[255];
    if (t < NC) table[(size_t)b * NC + t] = lds[t] - v;  // exclusive
}

// exclusive scan over bucket totals -> bstart
__global__ void k_scan_buckets(const int* __restrict__ btot, int* __restrict__ bstart,
                               int NB) {
    __shared__ int lds[MAXNB];
    int t = threadIdx.x;   // blockDim = 1024
    int v = (t < NB) ? btot[t] : 0;
    lds[t] = v;
    __syncthreads();
    for (int d = 1; d < 1024; d <<= 1) {
        int add = (t >= d) ? lds[t - d] : 0;
        __syncthreads();
        lds[t] += add;
        __syncthreads();
    }
    if (t < NB) bstart[t] = lds[t] - v;
}

// partition scatter: position from LDS cursors (no global atomics)
// sorted[p] = { meta = row | (col_local << 25), w }
__global__ void k_pscatter(const int* __restrict__ row, const int* __restrict__ col,
                           const float* __restrict__ w, const int* __restrict__ table,
                           const int* __restrict__ bstart, float2* __restrict__ sorted,
                           int NB, int NC, int E) {
    __shared__ int lcur[MAXNB];
    int chunk = blockIdx.x;
    int c0 = chunk * CHUNK, c1 = min(c0 + CHUNK, E);
    for (int b = threadIdx.x; b < NB; b += blockDim.x)
        lcur[b] = bstart[b] + table[(size_t)b * NC + chunk];
    __syncthreads();
    for (int e = c0 + threadIdx.x; e < c1; e += blockDim.x) {
        int c = col[e];
        int b = c >> BSH;
        int p = atomicAdd(&lcur[b], 1);
        float2 pr;
        pr.x = __int_as_float(row[e] | ((c & (NPB - 1)) << 25));
        pr.y = w[e];
        sorted[p] = pr;
    }
}

// per bucket: deg = 1 + sum(w) via LDS accumulation; dinv = rsqrt(deg)
__global__ void k_degv(const float2* __restrict__ sorted, const int* __restrict__ bstart,
                       const int* __restrict__ btot, float* __restrict__ dinv, int n) {
    __shared__ float acc[NPB];
    int b = blockIdx.x;
    for (int i = threadIdx.x; i < NPB; i += blockDim.x) acc[i] = 0.f;
    __syncthreads();
    int s = bstart[b], epos = s + btot[b];
    for (int e = s + threadIdx.x; e < epos; e += blockDim.x) {
        float2 pr = sorted[e];
        int cl = ((unsigned)__float_as_int(pr.x)) >> 25;
        atomicAdd(&acc[cl], pr.y);
    }
    __syncthreads();
    for (int i = threadIdx.x; i < NPB; i += blockDim.x) {
        int node = b * NPB + i;
        if (node < n) dinv[node] = rsqrtf(1.0f + acc[i]);
    }
}

// per bucket: out[c] = dinv_c * sum_e( h[r]*dinv_r*w ) + dinv_c^2*h[c] + bias
// 16-lane feature groups, LDS f32 atomics (stride 17 to spread banks)
__global__ void k_gather(const float2* __restrict__ sorted, const int* __restrict__ bstart,
                         const int* __restrict__ btot, const float* __restrict__ dinv,
                         const float* __restrict__ h, const float* __restrict__ bias,
                         float* __restrict__ out, int n) {
    __shared__ float acc[NPB * 17];
    int b = blockIdx.x, t = threadIdx.x;
    for (int i = t; i < NPB * 17; i += GT) acc[i] = 0.f;
    __syncthreads();
    int s = bstart[b], epos = s + btot[b];
    int f = t & 15;
    int g = t >> 4;                 // 0..31 edge subgroups
    for (int e = s + g; e < epos; e += 32) {
        float2 pr = sorted[e];
        unsigned m = (unsigned)__float_as_int(pr.x);
        int r = (int)(m & 0x1FFFFFFu);
        int cl = (int)(m >> 25);
        float nw = dinv[r] * pr.y;
        atomicAdd(&acc[cl * 17 + f], h[(size_t)r * NF + f] * nw);
    }
    __syncthreads();
    for (int i = t; i < NPB * NF; i += GT) {
        int nl = i >> 4, ff = i & 15;
        int node = b * NPB + nl;
        if (node < n) {
            float dc = dinv[node];
            out[(size_t)node * NF + ff] =
                fmaf(dc, acc[nl * 17 + ff],
                     fmaf(dc * dc, h[(size_t)node * NF + ff], bias[ff]));
        }
    }
}

// ==================== fallback (global-atomic scatter) =====================

__global__ void k_deg_init(float* __restrict__ deg, int n) {
    int i = blockIdx.x * blockDim.x + threadIdx.x;
    if (i < n) deg[i] = 1.0f;
}
__global__ void k_deg_acc(const int* __restrict__ col, const float* __restrict__ w,
                          float* __restrict__ deg, int E) {
    int e = blockIdx.x * blockDim.x + threadIdx.x;
    if (e < E) atomicAdd(&deg[col[e]], w[e]);
}
__global__ void k_dinv_ip(float* __restrict__ d, int n) {
    int i = blockIdx.x * blockDim.x + threadIdx.x;
    if (i < n) d[i] = rsqrtf(d[i]);
}
__global__ void k_init_out(const float* __restrict__ h, const float* __restrict__ dinv,
                           const float* __restrict__ bias, float* __restrict__ out, int n) {
    int i = blockIdx.x * blockDim.x + threadIdx.x;
    if (i >= n) return;
    float s = dinv[i] * dinv[i];
    #pragma unroll
    for (int f = 0; f < NF; ++f)
        out[(size_t)i * NF + f] = fmaf(h[(size_t)i * NF + f], s, bias[f]);
}
__global__ void k_scatter(const int* __restrict__ row, const int* __restrict__ col,
                          const float* __restrict__ w, const float* __restrict__ dinv,
                          const float* __restrict__ h, float* __restrict__ out, int E) {
    int e = blockIdx.x * blockDim.x + threadIdx.x;
    if (e >= E) return;
    int r = row[e], c = col[e];
    float norm = dinv[r] * w[e] * dinv[c];
    #pragma unroll
    for (int f = 0; f < NF; ++f)
        atomicAdd(&out[(size_t)c * NF + f], h[(size_t)r * NF + f] * norm);
}

// ===========================================================================

extern "C" void kernel_launch(void* const* d_in, const int* in_sizes, int n_in,
                              void* d_out, int out_size, void* d_ws, size_t ws_size,
                              hipStream_t stream) {
    const float* x  = (const float*)d_in[0];
    const int*   ei = (const int*)d_in[1];   // int32 (verified round 1)
    const float* w  = (const float*)d_in[2];
    const float* W1 = (const float*)d_in[3];
    const float* b1 = (const float*)d_in[4];
    const float* W2 = (const float*)d_in[5];
    const float* b2 = (const float*)d_in[6];
    float* out = (float*)d_out;

    const int n = in_sizes[0] / FI;          // 100000
    const int E = in_sizes[2];               // 6400000
    const int* row = ei;
    const int* col = ei + E;

    const int B  = 256;
    const int gn = (n + B - 1) / B;
    const int gE = (E + B - 1) / B;
    const int NB = (n + NPB - 1) / NPB;      // 782
    const int NC = (E + CHUNK - 1) / CHUNK;  // 196

    // ws layout (4B units): sorted(2E) | table(NB*NC) | btot(NB) | bstart(NB)
    //                       | dinv(n) | h(16n) | out1(16n)
    size_t need = ((size_t)2 * E + (size_t)NB * NC + 2 * (size_t)NB + 33 * (size_t)n) * 4;
    bool ok = (ws_size >= need) && (NB <= MAXNB) && (NC <= 256) && (n < (1 << 25));

    if (ok) {
        float*  ws     = (float*)d_ws;
        float2* sorted = (float2*)ws;
        int*    table  = (int*)(ws + 2 * (size_t)E);
        int*    btot   = table + (size_t)NB * NC;
        int*    bstart = btot + NB;
        float*  dinv   = (float*)(bstart + NB);
        float*  h      = dinv + n;                   // h1
        float*  out1   = h + 16 * (size_t)n;         // out1, then h2 in place

        k_h1<<<gn, B, 0, stream>>>(x, W1, h, n);
        k_phist<<<NC, 1024, 0, stream>>>(col, table, NB, NC, E);
        k_scan_chunks<<<NB, 256, 0, stream>>>(table, btot, NC);
        k_scan_buckets<<<1, 1024, 0, stream>>>(btot, bstart, NB);
        k_pscatter<<<NC, 1024, 0, stream>>>(row, col, w, table, bstart, sorted, NB, NC, E);
        k_degv<<<NB, 256, 0, stream>>>(sorted, bstart, btot, dinv, n);

        k_gather<<<NB, GT, 0, stream>>>(sorted, bstart, btot, dinv, h, b1, out1, n);
        k_h2<<<gn, B, 0, stream>>>(out1, W2, n);     // out1 -> h2 in place
        k_gather<<<NB, GT, 0, stream>>>(sorted, bstart, btot, dinv, out1, b2, out, n);
    } else {
        // fallback: global-atomic scatter path (13.2 MB ws), known-correct
        float* ws   = (float*)d_ws;
        float* dinv = ws;
        float* h    = ws + (size_t)n;
        float* out1 = h + 16 * (size_t)n;

        k_h1<<<gn, B, 0, stream>>>(x, W1, h, n);
        k_deg_init<<<gn, B, 0, stream>>>(dinv, n);
        k_deg_acc<<<gE, B, 0, stream>>>(col, w, dinv, E);
        k_dinv_ip<<<gn, B, 0, stream>>>(dinv, n);
        k_init_out<<<gn, B, 0, stream>>>(h, dinv, b1, out1, n);
        k_scatter<<<gE, B, 0, stream>>>(row, col, w, dinv, h, out1, E);
        k_h2<<<gn, B, 0, stream>>>(out1, W2, n);
        k_init_out<<<gn, B, 0, stream>>>(out1, dinv, b2, out, n);
        k_scatter<<<gE, B, 0, stream>>>(row, col, w, dinv, out1, out, E);
    }
}

// Round 6
// 1356.127 us; speedup vs baseline: 1.0868x; 1.0868x over previous
//
#include <hip/hip_runtime.h>

#define NF 16          // feature width of h / output
#define FI 8           // input feature width
#define NPB 64         // nodes per bucket
#define BSH 6          // log2(NPB)
#define CHUNK 65536    // edges per partition chunk
#define MAXNB 2048     // max buckets supported by LDS tables
#define GT 256         // gather block threads
#define NSG 16         // edge subgroups per gather block (GT/16)

// ---------------------------------------------------------------------------
// h1 = x @ W1   (n x 8) @ (8 x 16)
// ---------------------------------------------------------------------------
__global__ void k_h1(const float* __restrict__ x, const float* __restrict__ W1,
                     float* __restrict__ h, int n) {
    int i = blockIdx.x * blockDim.x + threadIdx.x;
    if (i >= n) return;
    const float4* xp = reinterpret_cast<const float4*>(x + (size_t)i * FI);
    float4 a = xp[0], b = xp[1];
    float xi[FI] = {a.x, a.y, a.z, a.w, b.x, b.y, b.z, b.w};
    float* hp = h + (size_t)i * NF;
    #pragma unroll
    for (int f = 0; f < NF; ++f) {
        float acc = 0.f;
        #pragma unroll
        for (int k = 0; k < FI; ++k) acc = fmaf(xi[k], W1[k * NF + f], acc);
        hp[f] = acc;
    }
}

// h2 = relu(src) @ W2 -> dst
__global__ void k_h2(const float* __restrict__ src, const float* __restrict__ W2,
                     float* __restrict__ dst, int n) {
    int i = blockIdx.x * blockDim.x + threadIdx.x;
    if (i >= n) return;
    float hi[NF];
    const float4* ip = reinterpret_cast<const float4*>(src + (size_t)i * NF);
    #pragma unroll
    for (int q = 0; q < 4; ++q) {
        float4 v = ip[q];
        hi[q * 4 + 0] = fmaxf(v.x, 0.f);
        hi[q * 4 + 1] = fmaxf(v.y, 0.f);
        hi[q * 4 + 2] = fmaxf(v.z, 0.f);
        hi[q * 4 + 3] = fmaxf(v.w, 0.f);
    }
    float4* op = reinterpret_cast<float4*>(dst + (size_t)i * NF);
    #pragma unroll
    for (int q = 0; q < 4; ++q) {
        float4 o;
        float* ov = &o.x;
        #pragma unroll
        for (int j = 0; j < 4; ++j) {
            int f = q * 4 + j;
            float acc = 0.f;
            #pragma unroll
            for (int k = 0; k < NF; ++k) acc = fmaf(hi[k], W2[k * NF + f], acc);
            ov[j] = acc;
        }
        op[q] = o;
    }
}

// ======================= radix-partition CSR build =========================

// per-chunk LDS histogram of bucket ids -> table[b*NC + chunk]
__global__ void k_phist(const int* __restrict__ col, int* __restrict__ table,
                        int NB, int NC, int E) {
    __shared__ int lh[MAXNB];
    int c0 = blockIdx.x * CHUNK;
    int c1 = min(c0 + CHUNK, E);
    for (int i = threadIdx.x; i < NB; i += blockDim.x) lh[i] = 0;
    __syncthreads();
    for (int e = c0 + threadIdx.x; e < c1; e += blockDim.x)
        atomicAdd(&lh[col[e] >> BSH], 1);
    __syncthreads();
    for (int b = threadIdx.x; b < NB; b += blockDim.x)
        table[(size_t)b * NC + blockIdx.x] = lh[b];
}

// per bucket: exclusive scan over its NC chunk counts (in place); btot[b]=total
__global__ void k_scan_chunks(int* __restrict__ table, int* __restrict__ btot,
                              int NC) {
    __shared__ int lds[256];
    int b = blockIdx.x, t = threadIdx.x;
    int v = (t < NC) ? table[(size_t)b * NC + t] : 0;
    lds[t] = v;
    __syncthreads();
    for (int d = 1; d < 256; d <<= 1) {
        int add = (t >= d) ? lds[t - d] : 0;
        __syncthreads();
        lds[t] += add;
        __syncthreads();
    }
    if (t == 255) btot[b] = lds[255];
    if (t < NC) table[(size_t)b * NC + t] = lds[t] - v;  // exclusive
}

// exclusive scan over bucket totals -> bstart (2 elements per thread, NB<=2048)
__global__ void k_scan_buckets(const int* __restrict__ btot, int* __restrict__ bstart,
                               int NB) {
    __shared__ int lds[1024];
    int t = threadIdx.x;   // blockDim = 1024
    int i0 = 2 * t, i1 = 2 * t + 1;
    int a = (i0 < NB) ? btot[i0] : 0;
    int b = (i1 < NB) ? btot[i1] : 0;
    lds[t] = a + b;
    __syncthreads();
    for (int d = 1; d < 1024; d <<= 1) {
        int add = (t >= d) ? lds[t - d] : 0;
        __syncthreads();
        lds[t] += add;
        __syncthreads();
    }
    int excl = t ? lds[t - 1] : 0;
    if (i0 < NB) bstart[i0] = excl;
    if (i1 < NB) bstart[i1] = excl + a;
}

// partition scatter: position from LDS cursors (no global atomics)
// sorted[p] = { meta = row | (col_local << 25), w }
__global__ void k_pscatter(const int* __restrict__ row, const int* __restrict__ col,
                           const float* __restrict__ w, const int* __restrict__ table,
                           const int* __restrict__ bstart, float2* __restrict__ sorted,
                           int NB, int NC, int E) {
    __shared__ int lcur[MAXNB];
    int chunk = blockIdx.x;
    int c0 = chunk * CHUNK, c1 = min(c0 + CHUNK, E);
    for (int b = threadIdx.x; b < NB; b += blockDim.x)
        lcur[b] = bstart[b] + table[(size_t)b * NC + chunk];
    __syncthreads();
    for (int e = c0 + threadIdx.x; e < c1; e += blockDim.x) {
        int c = col[e];
        int b = c >> BSH;
        int p = atomicAdd(&lcur[b], 1);
        float2 pr;
        pr.x = __int_as_float(row[e] | ((c & (NPB - 1)) << 25));
        pr.y = w[e];
        sorted[p] = pr;
    }
}

// per bucket: deg = 1 + sum(w) via LDS accumulation; dinv = rsqrt(deg)
__global__ void k_degv(const float2* __restrict__ sorted, const int* __restrict__ bstart,
                       const int* __restrict__ btot, float* __restrict__ dinv, int n) {
    __shared__ float acc[NPB];
    int b = blockIdx.x;
    for (int i = threadIdx.x; i < NPB; i += blockDim.x) acc[i] = 0.f;
    __syncthreads();
    int s = bstart[b], epos = s + btot[b];
    #pragma unroll 4
    for (int e = s + threadIdx.x; e < epos; e += blockDim.x) {
        float2 pr = sorted[e];
        int cl = ((unsigned)__float_as_int(pr.x)) >> 25;
        atomicAdd(&acc[cl], pr.y);
    }
    __syncthreads();
    for (int i = threadIdx.x; i < NPB; i += blockDim.x) {
        int node = b * NPB + i;
        if (node < n) dinv[node] = rsqrtf(1.0f + acc[i]);
    }
}

// per bucket: out[c] = dinv_c * sum_e( h[r]*dinv_r*w ) + dinv_c^2*h[c] + bias
// 16-lane feature groups; 4x unrolled for memory-level parallelism
__global__ void k_gather(const float2* __restrict__ sorted, const int* __restrict__ bstart,
                         const int* __restrict__ btot, const float* __restrict__ dinv,
                         const float* __restrict__ h, const float* __restrict__ bias,
                         float* __restrict__ out, int n) {
    __shared__ float acc[NPB * 17];
    int b = blockIdx.x, t = threadIdx.x;
    for (int i = t; i < NPB * 17; i += GT) acc[i] = 0.f;
    __syncthreads();
    int s = bstart[b];
    int cnt = btot[b];
    int f = t & 15;
    int g = t >> 4;                 // 0..NSG-1 edge subgroups
    const float2* sp = sorted + s;
    int e = g;
    for (; e + 3 * NSG < cnt; e += 4 * NSG) {
        float2 p0 = sp[e];
        float2 p1 = sp[e + NSG];
        float2 p2 = sp[e + 2 * NSG];
        float2 p3 = sp[e + 3 * NSG];
        unsigned m0 = (unsigned)__float_as_int(p0.x);
        unsigned m1 = (unsigned)__float_as_int(p1.x);
        unsigned m2 = (unsigned)__float_as_int(p2.x);
        unsigned m3 = (unsigned)__float_as_int(p3.x);
        int r0 = (int)(m0 & 0x1FFFFFFu);
        int r1 = (int)(m1 & 0x1FFFFFFu);
        int r2 = (int)(m2 & 0x1FFFFFFu);
        int r3 = (int)(m3 & 0x1FFFFFFu);
        float d0 = dinv[r0], d1 = dinv[r1], d2 = dinv[r2], d3 = dinv[r3];
        float v0 = h[(size_t)r0 * NF + f];
        float v1 = h[(size_t)r1 * NF + f];
        float v2 = h[(size_t)r2 * NF + f];
        float v3 = h[(size_t)r3 * NF + f];
        atomicAdd(&acc[(m0 >> 25) * 17 + f], v0 * (d0 * p0.y));
        atomicAdd(&acc[(m1 >> 25) * 17 + f], v1 * (d1 * p1.y));
        atomicAdd(&acc[(m2 >> 25) * 17 + f], v2 * (d2 * p2.y));
        atomicAdd(&acc[(m3 >> 25) * 17 + f], v3 * (d3 * p3.y));
    }
    for (; e < cnt; e += NSG) {
        float2 p = sp[e];
        unsigned m = (unsigned)__float_as_int(p.x);
        int r = (int)(m & 0x1FFFFFFu);
        atomicAdd(&acc[(m >> 25) * 17 + f], h[(size_t)r * NF + f] * (dinv[r] * p.y));
    }
    __syncthreads();
    for (int i = t; i < NPB * NF; i += GT) {
        int nl = i >> 4, ff = i & 15;
        int node = b * NPB + nl;
        if (node < n) {
            float dc = dinv[node];
            out[(size_t)node * NF + ff] =
                fmaf(dc, acc[nl * 17 + ff],
                     fmaf(dc * dc, h[(size_t)node * NF + ff], bias[ff]));
        }
    }
}

// ==================== fallback (global-atomic scatter) =====================

__global__ void k_deg_init(float* __restrict__ deg, int n) {
    int i = blockIdx.x * blockDim.x + threadIdx.x;
    if (i < n) deg[i] = 1.0f;
}
__global__ void k_deg_acc(const int* __restrict__ col, const float* __restrict__ w,
                          float* __restrict__ deg, int E) {
    int e = blockIdx.x * blockDim.x + threadIdx.x;
    if (e < E) atomicAdd(&deg[col[e]], w[e]);
}
__global__ void k_dinv_ip(float* __restrict__ d, int n) {
    int i = blockIdx.x * blockDim.x + threadIdx.x;
    if (i < n) d[i] = rsqrtf(d[i]);
}
__global__ void k_init_out(const float* __restrict__ h, const float* __restrict__ dinv,
                           const float* __restrict__ bias, float* __restrict__ out, int n) {
    int i = blockIdx.x * blockDim.x + threadIdx.x;
    if (i >= n) return;
    float s = dinv[i] * dinv[i];
    #pragma unroll
    for (int f = 0; f < NF; ++f)
        out[(size_t)i * NF + f] = fmaf(h[(size_t)i * NF + f], s, bias[f]);
}
__global__ void k_scatter(const int* __restrict__ row, const int* __restrict__ col,
                          const float* __restrict__ w, const float* __restrict__ dinv,
                          const float* __restrict__ h, float* __restrict__ out, int E) {
    int e = blockIdx.x * blockDim.x + threadIdx.x;
    if (e >= E) return;
    int r = row[e], c = col[e];
    float norm = dinv[r] * w[e] * dinv[c];
    #pragma unroll
    for (int f = 0; f < NF; ++f)
        atomicAdd(&out[(size_t)c * NF + f], h[(size_t)r * NF + f] * norm);
}

// ===========================================================================

extern "C" void kernel_launch(void* const* d_in, const int* in_sizes, int n_in,
                              void* d_out, int out_size, void* d_ws, size_t ws_size,
                              hipStream_t stream) {
    const float* x  = (const float*)d_in[0];
    const int*   ei = (const int*)d_in[1];   // int32 (verified round 1)
    const float* w  = (const float*)d_in[2];
    const float* W1 = (const float*)d_in[3];
    const float* b1 = (const float*)d_in[4];
    const float* W2 = (const float*)d_in[5];
    const float* b2 = (const float*)d_in[6];
    float* out = (float*)d_out;

    const int n = in_sizes[0] / FI;          // 100000
    const int E = in_sizes[2];               // 6400000
    const int* row = ei;
    const int* col = ei + E;

    const int B  = 256;
    const int gn = (n + B - 1) / B;
    const int gE = (E + B - 1) / B;
    const int NB = (n + NPB - 1) / NPB;      // 1563
    const int NC = (E + CHUNK - 1) / CHUNK;  // 98

    // ws layout (4B units): sorted(2E) | table(NB*NC) | btot(NB) | bstart(NB)
    //                       | dinv(n) | h(16n)           [out1 eliminated: d_out used]
    size_t need = ((size_t)2 * E + (size_t)NB * NC + 2 * (size_t)NB + 17 * (size_t)n) * 4;
    bool ok = (ws_size >= need) && (NB <= MAXNB) && (NC <= 256) && (n < (1 << 25));

    if (ok) {
        float*  ws     = (float*)d_ws;
        float2* sorted = (float2*)ws;
        int*    table  = (int*)(ws + 2 * (size_t)E);
        int*    btot   = table + (size_t)NB * NC;
        int*    bstart = btot + NB;
        float*  dinv   = (float*)(bstart + NB);
        float*  h      = dinv + n;                   // h1, later h2

        k_h1<<<gn, B, 0, stream>>>(x, W1, h, n);
        k_phist<<<NC, 1024, 0, stream>>>(col, table, NB, NC, E);
        k_scan_chunks<<<NB, 256, 0, stream>>>(table, btot, NC);
        k_scan_buckets<<<1, 1024, 0, stream>>>(btot, bstart, NB);
        k_pscatter<<<NC, 1024, 0, stream>>>(row, col, w, table, bstart, sorted, NB, NC, E);
        k_degv<<<NB, 256, 0, stream>>>(sorted, bstart, btot, dinv, n);

        k_gather<<<NB, GT, 0, stream>>>(sorted, bstart, btot, dinv, h, b1, out, n);
        k_h2<<<gn, B, 0, stream>>>(out, W2, h, n);   // d_out -> h2
        k_gather<<<NB, GT, 0, stream>>>(sorted, bstart, btot, dinv, h, b2, out, n);
    } else {
        // fallback: global-atomic scatter path (13.2 MB ws), known-correct
        float* ws   = (float*)d_ws;
        float* dinv = ws;
        float* h    = ws + (size_t)n;
        float* out1 = h + 16 * (size_t)n;

        k_h1<<<gn, B, 0, stream>>>(x, W1, h, n);
        k_deg_init<<<gn, B, 0, stream>>>(dinv, n);
        k_deg_acc<<<gE, B, 0, stream>>>(col, w, dinv, E);
        k_dinv_ip<<<gn, B, 0, stream>>>(dinv, n);
        k_init_out<<<gn, B, 0, stream>>>(h, dinv, b1, out1, n);
        k_scatter<<<gE, B, 0, stream>>>(row, col, w, dinv, h, out1, E);
        k_h2<<<gn, B, 0, stream>>>(out1, W2, out1, n);
        k_init_out<<<gn, B, 0, stream>>>(out1, dinv, b2, out, n);
        k_scatter<<<gE, B, 0, stream>>>(row, col, w, dinv, out1, out, E);
    }
}